// Round 3
// baseline (3749.252 us; speedup 1.0000x reference)
//
#include <hip/hip_runtime.h>

#pragma clang fp contract(off)

#define HQ 384
#define WQ 384
#define NB 4
#define NC 64
#define HF 48
#define WF 48
#define HID 256
#define NPIX (NB * HQ * WQ)
#define PPB 32  // pixels per block

// ---------------------------------------------------------------------------
// Nearest-sample index per PyTorch grid_sample(nearest, align_corners=False):
//   ix = ((g + 1) * 48 - 1) * 0.5, round half-even, zero-pad OOB.
// Exact f32 op sequence (contraction disabled file-wide).
// ---------------------------------------------------------------------------
__device__ __forceinline__ int nearest_idx(float g, bool& valid) {
    float t  = (g + 1.0f) * 48.0f;
    float ix = (t - 1.0f) * 0.5f;
    float r  = rintf(ix);          // v_rndne_f32: round half to even
    int   i  = (int)r;
    if (i < 0 || i > 47) valid = false;
    return i < 0 ? 0 : (i > 47 ? 47 : i);
}

// ---------------------------------------------------------------------------
// One MLP layer: dst[p][j] = act(sum_k src[p][k] * W[k][j] + bias[j])
// 256 threads cover 32 px x 256 feats; per-thread tile 4 px x 8 feats.
// src/dst live in LDS; W/bias stream through L1/L2 (shared across blocks).
// ---------------------------------------------------------------------------
template <int K, bool RELU>
__device__ __forceinline__ void mlp_layer(const float* __restrict__ src, int sstride,
                                          const float* __restrict__ W,
                                          const float* __restrict__ bias,
                                          float* __restrict__ dst, int dstride) {
    const int tid = threadIdx.x;
    const int jt = tid & 31;   // j-tile id
    const int pt = tid >> 5;   // p-tile id
    const int j0 = jt * 8;
    const int p0 = pt * 4;

    float acc[4][8];
#pragma unroll
    for (int i = 0; i < 4; ++i)
#pragma unroll
        for (int j = 0; j < 8; ++j) acc[i][j] = 0.0f;

    constexpr int KM = K & ~3;
    for (int k = 0; k < KM; k += 4) {
        float4 hv[4];
#pragma unroll
        for (int i = 0; i < 4; ++i)
            hv[i] = *(const float4*)(src + (p0 + i) * sstride + k);
#pragma unroll
        for (int kk = 0; kk < 4; ++kk) {
            const float* wr = W + (k + kk) * HID + j0;
            float4 w0 = *(const float4*)(wr);
            float4 w1 = *(const float4*)(wr + 4);
            float wv[8] = {w0.x, w0.y, w0.z, w0.w, w1.x, w1.y, w1.z, w1.w};
#pragma unroll
            for (int i = 0; i < 4; ++i) {
                float h = (&hv[i].x)[kk];
#pragma unroll
                for (int j = 0; j < 8; ++j)
                    acc[i][j] = __builtin_fmaf(h, wv[j], acc[i][j]);
            }
        }
    }
    if constexpr (KM < K) {
        for (int kk = KM; kk < K; ++kk) {
            const float* wr = W + kk * HID + j0;
            float4 w0 = *(const float4*)(wr);
            float4 w1 = *(const float4*)(wr + 4);
            float wv[8] = {w0.x, w0.y, w0.z, w0.w, w1.x, w1.y, w1.z, w1.w};
#pragma unroll
            for (int i = 0; i < 4; ++i) {
                float h = src[(p0 + i) * sstride + kk];
#pragma unroll
                for (int j = 0; j < 8; ++j)
                    acc[i][j] = __builtin_fmaf(h, wv[j], acc[i][j]);
            }
        }
    }

    float4 bv0 = *(const float4*)(bias + j0);
    float4 bv1 = *(const float4*)(bias + j0 + 4);
    float bv[8] = {bv0.x, bv0.y, bv0.z, bv0.w, bv1.x, bv1.y, bv1.z, bv1.w};
#pragma unroll
    for (int i = 0; i < 4; ++i) {
        float o[8];
#pragma unroll
        for (int j = 0; j < 8; ++j) {
            float v = acc[i][j] + bv[j];
            o[j] = RELU ? fmaxf(v, 0.0f) : v;
        }
        *(float4*)(dst + (p0 + i) * dstride + j0)     = make_float4(o[0], o[1], o[2], o[3]);
        *(float4*)(dst + (p0 + i) * dstride + j0 + 4) = make_float4(o[4], o[5], o[6], o[7]);
    }
}

// ---------------------------------------------------------------------------
// Fused LIIF kernel: feature build (LDS) + 5-layer MLP + output write.
// ---------------------------------------------------------------------------
extern "C" __global__ void __launch_bounds__(256, 2)
liif_kernel(const float* __restrict__ x, const float* __restrict__ coord,
            const float* __restrict__ cell, const float* __restrict__ lr,
            const float* __restrict__ W0, const float* __restrict__ b0,
            const float* __restrict__ W1, const float* __restrict__ b1,
            const float* __restrict__ W2, const float* __restrict__ b2,
            const float* __restrict__ W3, const float* __restrict__ b3,
            const float* __restrict__ W4, const float* __restrict__ b4,
            float* __restrict__ out) {
    __shared__ float sIn[PPB][72];   //  9.2 KB
    __shared__ float sA[PPB][264];   // 33.8 KB
    __shared__ float sB[PPB][264];   // 33.8 KB  -> total 76.8 KB, 2 blocks/CU

    const int tid = threadIdx.x;

    // ---------------- stage 1: 71-dim feature per pixel -> sIn ----------------
    {
        const int p   = tid >> 3;  // pixel within block (0..31)
        const int sub = tid & 7;   // 8 threads cooperate per pixel
        const int g   = blockIdx.x * PPB + p;
        const int b   = g / (HQ * WQ);

        const float gy = coord[(size_t)g * 2 + 0];
        const float gx = coord[(size_t)g * 2 + 1];

        bool vmain = true;
        const int ixn = nearest_idx(gx, vmain);
        const int iyn = nearest_idx(gy, vmain);

        // q_feat: 64 channels, 8 per thread
        const float* xb = x + (((size_t)b * NC) * HF + iyn) * WF + ixn;
#pragma unroll
        for (int c = sub; c < NC; c += 8)
            sIn[p][c] = vmain ? xb[(size_t)c * HF * WF] : 0.0f;

        if (sub == 0) {
            // q_coord via feat_coord formula: ((2*i+1)/48 - 1), zero if invalid
            float qy = vmain ? ((2.0f * (float)iyn + 1.0f) / 48.0f - 1.0f) : 0.0f;
            float qx = vmain ? ((2.0f * (float)ixn + 1.0f) / 48.0f - 1.0f) : 0.0f;
            sIn[p][64] = (gy - qy) * 48.0f;
            sIn[p][65] = (gx - qx) * 48.0f;
            sIn[p][66] = cell[b * 2 + 0] * 48.0f;
            sIn[p][67] = cell[b * 2 + 1] * 48.0f;
            sIn[p][71] = 0.0f;  // pad (never read)
        }
        if (sub >= 1 && sub <= 3) {
            // rgb_std channel ch over 4 diagonally shifted nearest LR samples
            const int ch = sub - 1;
            const float c148 = (float)(1.0 / 48.0);       // python f64 1/48 -> f32
            const float LO = (float)(-1.0 + 1e-6);
            const float HI = (float)(1.0 - 1e-6);
            float v[4];
            int s = 0;
#pragma unroll
            for (int a = 0; a < 2; ++a) {        // vx in (-1, +1) applied to gy
                const float vx = (a == 0) ? -c148 : c148;
#pragma unroll
                for (int q = 0; q < 2; ++q) {    // vy in (-1, +1) applied to gx
                    const float vy = (q == 0) ? -c148 : c148;
                    float cy = (gy + vx) + 1e-6f;
                    cy = fminf(fmaxf(cy, LO), HI);
                    float cx = (gx + vy) + 1e-6f;
                    cx = fminf(fmaxf(cx, LO), HI);
                    bool vv = true;
                    int jx = nearest_idx(cx, vv);
                    int jy = nearest_idx(cy, vv);
                    v[s++] = vv ? lr[(((size_t)b * 3 + ch) * HF + jy) * WF + jx] : 0.0f;
                }
            }
            float mean = (((v[0] + v[1]) + v[2]) + v[3]) / 4.0f;
            float d0 = v[0] - mean, d1 = v[1] - mean;
            float d2 = v[2] - mean, d3 = v[3] - mean;
            float var = (((d0 * d0 + d1 * d1) + d2 * d2) + d3 * d3) / 3.0f;  // ddof=1
            sIn[p][68 + ch] = sqrtf(var);
        }
    }
    __syncthreads();

    // ---------------- stage 2: MLP ----------------
    mlp_layer<71, true>(&sIn[0][0], 72, W0, b0, &sA[0][0], 264);
    __syncthreads();
    mlp_layer<256, true>(&sA[0][0], 264, W1, b1, &sB[0][0], 264);
    __syncthreads();
    mlp_layer<256, true>(&sB[0][0], 264, W2, b2, &sA[0][0], 264);
    __syncthreads();
    mlp_layer<256, true>(&sA[0][0], 264, W3, b3, &sB[0][0], 264);
    __syncthreads();

    // ---------------- final layer: 256 -> 3, one thread per (pixel, out) ------
    if (tid < PPB * 3) {
        const int p = tid / 3;
        const int o = tid - p * 3;
        const float* src = &sB[p][0];
        float acc = 0.0f;
        for (int k = 0; k < 256; k += 4) {
            float4 h = *(const float4*)(src + k);
            acc = __builtin_fmaf(h.x, W4[(k + 0) * 3 + o], acc);
            acc = __builtin_fmaf(h.y, W4[(k + 1) * 3 + o], acc);
            acc = __builtin_fmaf(h.z, W4[(k + 2) * 3 + o], acc);
            acc = __builtin_fmaf(h.w, W4[(k + 3) * 3 + o], acc);
        }
        acc += b4[o];
        const int g   = blockIdx.x * PPB + p;
        const int b   = g / (HQ * WQ);
        const int rem = g - b * (HQ * WQ);
        out[((size_t)(b * 3 + o)) * (HQ * WQ) + rem] = acc;
    }
}

extern "C" void kernel_launch(void* const* d_in, const int* in_sizes, int n_in,
                              void* d_out, int out_size, void* d_ws, size_t ws_size,
                              hipStream_t stream) {
    const float* x     = (const float*)d_in[0];
    const float* coord = (const float*)d_in[1];
    const float* cell  = (const float*)d_in[2];
    const float* lr    = (const float*)d_in[3];
    const float* W0    = (const float*)d_in[4];
    const float* b0    = (const float*)d_in[5];
    const float* W1    = (const float*)d_in[6];
    const float* b1    = (const float*)d_in[7];
    const float* W2    = (const float*)d_in[8];
    const float* b2    = (const float*)d_in[9];
    const float* W3    = (const float*)d_in[10];
    const float* b3    = (const float*)d_in[11];
    const float* W4    = (const float*)d_in[12];
    const float* b4    = (const float*)d_in[13];

    liif_kernel<<<dim3(NPIX / PPB), dim3(256), 0, stream>>>(
        x, coord, cell, lr, W0, b0, W1, b1, W2, b2, W3, b3, W4, b4, (float*)d_out);
}

// Round 5
// 937.509 us; speedup vs baseline: 3.9992x; 3.9992x over previous
//
#include <hip/hip_runtime.h>

#pragma clang fp contract(off)

#define HQ 384
#define WQ 384
#define NC 64
#define HFD 48
#define HID 256
#define NPIX (4 * HQ * WQ)
#define PPB 64   // pixels per block

typedef _Float16 half8 __attribute__((ext_vector_type(8)));
typedef float f32x4 __attribute__((ext_vector_type(4)));
typedef unsigned int u32;
typedef unsigned short u16;

// ws layout in u32 units: per layer, A=W^T fragments, hi then lo.
// entry index = ((t*NS + s)*64 + lane)*4 + i ; L0: NT=16,NS=3 ; L1-3: NT=16,NS=8
#define O0H 0
#define O0L 12288
#define O1H 24576
#define O1L 57344
#define O2H 90112
#define O2L 122880
#define O3H 155648
#define O3L 188416
// total 221184 u32 = 884736 bytes of d_ws used

// ---------------------------------------------------------------------------
// f32 -> (f16 hi, f16 lo*2^11) split. x ≈ hi + lo/2048, error ~2^-22 rel.
// ---------------------------------------------------------------------------
__device__ __forceinline__ void split16(float x, u16& h, u16& l) {
    _Float16 hf = (_Float16)x;               // RNE
    float hb = (float)hf;                    // exact
    _Float16 lf = (_Float16)((x - hb) * 2048.0f);  // (x-hb) exact; *2^11 exact
    h = __builtin_bit_cast(u16, hf);
    l = __builtin_bit_cast(u16, lf);
}
__device__ __forceinline__ u32 pk(u16 a, u16 b) { return (u32)a | ((u32)b << 16); }
__device__ __forceinline__ float f16lo(u32 v) {
    return (float)__builtin_bit_cast(_Float16, (u16)(v & 0xffffu));
}
__device__ __forceinline__ float f16hi(u32 v) {
    return (float)__builtin_bit_cast(_Float16, (u16)(v >> 16));
}

// ---------------------------------------------------------------------------
// Nearest-sample index per grid_sample(nearest, align_corners=False).
// Exact f32 op sequence (contraction off file-wide). Validated in baseline.
// ---------------------------------------------------------------------------
__device__ __forceinline__ int nearest_idx(float g, bool& valid) {
    float t  = (g + 1.0f) * 48.0f;
    float ix = (t - 1.0f) * 0.5f;
    float r  = rintf(ix);          // round half to even
    int   i  = (int)r;
    if (i < 0 || i > 47) valid = false;
    return i < 0 ? 0 : (i > 47 ? 47 : i);
}

// ---------------------------------------------------------------------------
// Weight pre-pack: A = W^T as MFMA A-fragments (f16 hi / scaled-lo), coalesced.
// lane: row j' = 16t + (lane&15), k = 32s + 8*(lane>>4) + 2i (+1)
// ---------------------------------------------------------------------------
extern "C" __global__ void __launch_bounds__(256)
pack_w(const float* __restrict__ W0, const float* __restrict__ W1,
       const float* __restrict__ W2, const float* __restrict__ W3,
       u32* __restrict__ ws) {
    int gid = blockIdx.x * 256 + threadIdx.x;   // 0..110591
    const float* W; int NS, K, oh, ol, rem;
    if (gid < 12288)      { W = W0; NS = 3; K = 71;  oh = O0H; ol = O0L; rem = gid; }
    else if (gid < 45056) { W = W1; NS = 8; K = 256; oh = O1H; ol = O1L; rem = gid - 12288; }
    else if (gid < 77824) { W = W2; NS = 8; K = 256; oh = O2H; ol = O2L; rem = gid - 45056; }
    else                  { W = W3; NS = 8; K = 256; oh = O3H; ol = O3L; rem = gid - 77824; }
    int i = rem & 3, lane = (rem >> 2) & 63, ts = rem >> 8;
    int s = ts % NS, t = ts / NS;
    int jp = t * 16 + (lane & 15);
    int k0 = s * 32 + (lane >> 4) * 8 + 2 * i;
    float w0 = (k0 < K)     ? W[(size_t)k0 * HID + jp]       : 0.0f;
    float w1 = (k0 + 1 < K) ? W[(size_t)(k0 + 1) * HID + jp] : 0.0f;
    u16 h0, l0, h1, l1;
    split16(w0, h0, l0);
    split16(w1, h1, l1);
    ws[oh + rem] = pk(h0, h1);
    ws[ol + rem] = pk(l0, l1);
}

// ---------------------------------------------------------------------------
// One MFMA MLP layer: act' = relu(W^T · act + b).
// act in LDS as f16 hi/lo pairs, [64 rows(px)][128 u32(j-pairs)],
// 16B-unit XOR swizzle: physical unit = q ^ (row & 31).
// Wave owns 4 j'-tiles (T = wave*4+tt), all 4 px-tiles.
// ---------------------------------------------------------------------------
template <int NS>
__device__ __forceinline__ void mfma_layer(
    const u32* __restrict__ whi, const u32* __restrict__ wlo,
    const float* __restrict__ bias,
    u32* __restrict__ sHi, u32* __restrict__ sLo,
    int wave, int lane) {
    const int r = lane & 15, g = lane >> 4;
    f32x4 acc[4][4];
#pragma unroll
    for (int a = 0; a < 4; ++a)
#pragma unroll
        for (int b = 0; b < 4; ++b) acc[a][b] = f32x4{0.0f, 0.0f, 0.0f, 0.0f};
    const f32x4 zero = f32x4{0.0f, 0.0f, 0.0f, 0.0f};

    for (int s = 0; s < NS; ++s) {
        half8 ah[4], al[4];
#pragma unroll
        for (int tt = 0; tt < 4; ++tt) {
            int idx = (((wave * 4 + tt) * NS + s) * 64 + lane) * 4;
            ah[tt] = __builtin_bit_cast(half8, *(const uint4*)(whi + idx));
            al[tt] = __builtin_bit_cast(half8, *(const uint4*)(wlo + idx));
        }
        half8 bh[4], bl[4];
#pragma unroll
        for (int p = 0; p < 4; ++p) {
            int rr = p * 16 + r;
            int qp = (s * 4 + g) ^ (rr & 31);
            int a = rr * 128 + qp * 4;
            bh[p] = __builtin_bit_cast(half8, *(const uint4*)(sHi + a));
            bl[p] = __builtin_bit_cast(half8, *(const uint4*)(sLo + a));
        }
#pragma unroll
        for (int tt = 0; tt < 4; ++tt)
#pragma unroll
            for (int p = 0; p < 4; ++p) {
                acc[tt][p] = __builtin_amdgcn_mfma_f32_16x16x32_f16(ah[tt], bh[p], acc[tt][p], 0, 0, 0);
                f32x4 a2 = __builtin_amdgcn_mfma_f32_16x16x32_f16(ah[tt], bl[p], zero, 0, 0, 0);
                a2 = __builtin_amdgcn_mfma_f32_16x16x32_f16(al[tt], bh[p], a2, 0, 0, 0);
#pragma unroll
                for (int e = 0; e < 4; ++e)
                    acc[tt][p][e] = __builtin_fmaf(a2[e], (1.0f / 2048.0f), acc[tt][p][e]);
            }
    }
    __syncthreads();   // everyone done READING act before overwrite

    // epilogue: bias + relu + split + LDS write (D: col px = lane&15, row j' = 4g+reg)
#pragma unroll
    for (int tt = 0; tt < 4; ++tt) {
        int T = wave * 4 + tt;
        int jb = T * 16 + g * 4;
        float bv0 = bias[jb + 0], bv1 = bias[jb + 1];
        float bv2 = bias[jb + 2], bv3 = bias[jb + 3];
#pragma unroll
        for (int p = 0; p < 4; ++p) {
            float v0 = fmaxf(acc[tt][p][0] + bv0, 0.0f);
            float v1 = fmaxf(acc[tt][p][1] + bv1, 0.0f);
            float v2 = fmaxf(acc[tt][p][2] + bv2, 0.0f);
            float v3 = fmaxf(acc[tt][p][3] + bv3, 0.0f);
            u16 h0, l0, h1, l1, h2, l2, h3, l3;
            split16(v0, h0, l0); split16(v1, h1, l1);
            split16(v2, h2, l2); split16(v3, h3, l3);
            int rr = p * 16 + r;
            int j2 = T * 8 + g * 2;
            int qp = (j2 >> 2) ^ (rr & 31);
            int a = rr * 128 + qp * 4 + (j2 & 3);
            sHi[a]     = pk(h0, h1);
            sHi[a + 1] = pk(h2, h3);
            sLo[a]     = pk(l0, l1);
            sLo[a + 1] = pk(l2, l3);
        }
    }
    __syncthreads();
}

// ---------------------------------------------------------------------------
// Fused LIIF kernel: feature build -> 4 MFMA layers -> small final layer.
// ---------------------------------------------------------------------------
extern "C" __global__ void __launch_bounds__(256, 2)
liif_mfma(const float* __restrict__ x, const float* __restrict__ coord,
          const float* __restrict__ cell, const float* __restrict__ lr,
          const float* __restrict__ b0, const float* __restrict__ b1,
          const float* __restrict__ b2, const float* __restrict__ b3,
          const float* __restrict__ W4, const float* __restrict__ b4,
          const u32* __restrict__ ws, float* __restrict__ out) {
    __shared__ u32 sHi[PPB * 128];   // 32 KB
    __shared__ u32 sLo[PPB * 128];   // 32 KB
    const int tid = threadIdx.x;
    const int wave = tid >> 6, lane = tid & 63;

    // ---------------- stage 1: 71-dim feature -> LDS f16 hi/lo --------------
    {
        const int px = tid >> 2, sub = tid & 3;
        const int gg = blockIdx.x * PPB + px;
        const int b = gg / (HQ * WQ);
        const float gy = coord[(size_t)gg * 2 + 0];
        const float gx = coord[(size_t)gg * 2 + 1];
        bool vmain = true;
        const int ixn = nearest_idx(gx, vmain);
        const int iyn = nearest_idx(gy, vmain);

        // 16 q_feat channels per thread -> logical units 2*sub, 2*sub+1
        const float* xb = x + (((size_t)b * NC) * HFD + iyn) * HFD + ixn;
        u32 hbuf[8], lbuf[8];
#pragma unroll
        for (int e = 0; e < 8; ++e) {
            int c = sub * 16 + e * 2;
            float v0 = vmain ? xb[(size_t)c * (HFD * HFD)] : 0.0f;
            float v1 = vmain ? xb[(size_t)(c + 1) * (HFD * HFD)] : 0.0f;
            u16 h0, l0, h1, l1;
            split16(v0, h0, l0);
            split16(v1, h1, l1);
            hbuf[e] = pk(h0, h1);
            lbuf[e] = pk(l0, l1);
        }
        {
            int qp = (2 * sub) ^ (px & 31);
            *(uint4*)(sHi + px * 128 + qp * 4) = make_uint4(hbuf[0], hbuf[1], hbuf[2], hbuf[3]);
            *(uint4*)(sLo + px * 128 + qp * 4) = make_uint4(lbuf[0], lbuf[1], lbuf[2], lbuf[3]);
            qp = (2 * sub + 1) ^ (px & 31);
            *(uint4*)(sHi + px * 128 + qp * 4) = make_uint4(hbuf[4], hbuf[5], hbuf[6], hbuf[7]);
            *(uint4*)(sLo + px * 128 + qp * 4) = make_uint4(lbuf[4], lbuf[5], lbuf[6], lbuf[7]);
        }
        if (sub == 0) {
            // extras: j = 64..71 -> logical unit 8
            float qyc = vmain ? ((2.0f * (float)iyn + 1.0f) / 48.0f - 1.0f) : 0.0f;
            float qxc = vmain ? ((2.0f * (float)ixn + 1.0f) / 48.0f - 1.0f) : 0.0f;
            float f64v = (gy - qyc) * 48.0f;
            float f65v = (gx - qxc) * 48.0f;
            float f66v = cell[b * 2 + 0] * 48.0f;
            float f67v = cell[b * 2 + 1] * 48.0f;

            // rgb_std over 4 diagonally shifted nearest LR samples (ddof=1)
            const float c148 = (float)(1.0 / 48.0);
            const float LO = (float)(-1.0 + 1e-6);
            const float HI = (float)(1.0 - 1e-6);
            float v[4][3];
#pragma unroll
            for (int a = 0; a < 2; ++a) {
                const float vx = (a == 0) ? -c148 : c148;
#pragma unroll
                for (int qq = 0; qq < 2; ++qq) {
                    const float vy = (qq == 0) ? -c148 : c148;
                    float cy = (gy + vx) + 1e-6f;
                    cy = fminf(fmaxf(cy, LO), HI);
                    float cx = (gx + vy) + 1e-6f;
                    cx = fminf(fmaxf(cx, LO), HI);
                    bool vv = true;
                    int jx = nearest_idx(cx, vv);
                    int jy = nearest_idx(cy, vv);
                    int si = a * 2 + qq;
#pragma unroll
                    for (int ch = 0; ch < 3; ++ch)
                        v[si][ch] = vv ? lr[(((size_t)b * 3 + ch) * HFD + jy) * HFD + jx] : 0.0f;
                }
            }
            float sd[3];
#pragma unroll
            for (int ch = 0; ch < 3; ++ch) {
                float mean = (((v[0][ch] + v[1][ch]) + v[2][ch]) + v[3][ch]) / 4.0f;
                float d0 = v[0][ch] - mean, d1 = v[1][ch] - mean;
                float d2 = v[2][ch] - mean, d3 = v[3][ch] - mean;
                float var = (((d0 * d0 + d1 * d1) + d2 * d2) + d3 * d3) / 3.0f;
                sd[ch] = sqrtf(var);
            }
            u16 h0, l0, h1, l1;
            u32 hb[4], lb[4];
            split16(f64v, h0, l0); split16(f65v, h1, l1); hb[0] = pk(h0, h1); lb[0] = pk(l0, l1);
            split16(f66v, h0, l0); split16(f67v, h1, l1); hb[1] = pk(h0, h1); lb[1] = pk(l0, l1);
            split16(sd[0], h0, l0); split16(sd[1], h1, l1); hb[2] = pk(h0, h1); lb[2] = pk(l0, l1);
            split16(sd[2], h0, l0); hb[3] = pk(h0, 0); lb[3] = pk(l0, 0);
            int qp = 8 ^ (px & 31);
            *(uint4*)(sHi + px * 128 + qp * 4) = make_uint4(hb[0], hb[1], hb[2], hb[3]);
            *(uint4*)(sLo + px * 128 + qp * 4) = make_uint4(lb[0], lb[1], lb[2], lb[3]);
        } else {
            // zero-pad logical units 9..11 (k = 72..95)
            int qp = (8 + sub) ^ (px & 31);
            *(uint4*)(sHi + px * 128 + qp * 4) = make_uint4(0, 0, 0, 0);
            *(uint4*)(sLo + px * 128 + qp * 4) = make_uint4(0, 0, 0, 0);
        }
    }
    __syncthreads();

    // ---------------- 4 hidden layers on the matrix pipe --------------------
    mfma_layer<3>(ws + O0H, ws + O0L, b0, sHi, sLo, wave, lane);
    mfma_layer<8>(ws + O1H, ws + O1L, b1, sHi, sLo, wave, lane);
    mfma_layer<8>(ws + O2H, ws + O2L, b2, sHi, sLo, wave, lane);
    mfma_layer<8>(ws + O3H, ws + O3L, b3, sHi, sLo, wave, lane);

    // ---------------- final 256 -> 3 (VALU, tiny) ---------------------------
    if (tid < PPB * 3) {
        int px = tid / 3, o = tid - px * 3;
        float acc = 0.0f;
        for (int q = 0; q < 32; ++q) {
            int qp = q ^ (px & 31);
            const u32* ph = sHi + px * 128 + qp * 4;
            const u32* pl = sLo + px * 128 + qp * 4;
#pragma unroll
            for (int uu = 0; uu < 4; ++uu) {
                u32 hv = ph[uu], lv = pl[uu];
                int j = q * 8 + uu * 2;
                float x0 = f16lo(hv) + f16lo(lv) * (1.0f / 2048.0f);
                float x1 = f16hi(hv) + f16hi(lv) * (1.0f / 2048.0f);
                acc = __builtin_fmaf(x0, W4[j * 3 + o], acc);
                acc = __builtin_fmaf(x1, W4[(j + 1) * 3 + o], acc);
            }
        }
        acc += b4[o];
        int gg = blockIdx.x * PPB + px;
        int b = gg / (HQ * WQ);
        int rem = gg - b * (HQ * WQ);
        out[((size_t)(b * 3 + o)) * (HQ * WQ) + rem] = acc;
    }
}

extern "C" void kernel_launch(void* const* d_in, const int* in_sizes, int n_in,
                              void* d_out, int out_size, void* d_ws, size_t ws_size,
                              hipStream_t stream) {
    const float* x     = (const float*)d_in[0];
    const float* coord = (const float*)d_in[1];
    const float* cell  = (const float*)d_in[2];
    const float* lr    = (const float*)d_in[3];
    const float* W0    = (const float*)d_in[4];
    const float* b0    = (const float*)d_in[5];
    const float* W1    = (const float*)d_in[6];
    const float* b1    = (const float*)d_in[7];
    const float* W2    = (const float*)d_in[8];
    const float* b2    = (const float*)d_in[9];
    const float* W3    = (const float*)d_in[10];
    const float* b3    = (const float*)d_in[11];
    const float* W4    = (const float*)d_in[12];
    const float* b4    = (const float*)d_in[13];
    u32* ws = (u32*)d_ws;

    pack_w<<<dim3(432), dim3(256), 0, stream>>>(W0, W1, W2, W3, ws);
    liif_mfma<<<dim3(NPIX / PPB), dim3(256), 0, stream>>>(
        x, coord, cell, lr, b0, b1, b2, b3, W4, b4, ws, (float*)d_out);
}